// Round 1
// baseline (113.866 us; speedup 1.0000x reference)
//
#include <hip/hip_runtime.h>

// Problem constants (from reference)
constexpr int B = 16384;
constexpr int T = 256;
constexpr int D = 8;
constexpr int F = 512;
constexpr int C = 16;
constexpr int L = 256;  // 2^D

struct FP { int fidx; float thr; };  // packed per-(t,d) node info, 8 B

// Kernel 1: per (t,d) argmax over F=512 feature weights, first-occurrence
// tie-break to match jnp.argmax. One wave per row; 4 rows per 256-thread block.
__global__ __launch_bounds__(256) void node_prep_kernel(
    const float* __restrict__ fw,      // (T, D, F)
    const float* __restrict__ thr,     // (T, D)
    FP* __restrict__ packed)           // (T*D)
{
    const int wave = threadIdx.x >> 6;
    const int lane = threadIdx.x & 63;
    const int row  = blockIdx.x * 4 + wave;          // [0, T*D)
    const float* base = fw + (size_t)row * F;

    float best = -INFINITY;
    int bidx = 0;
#pragma unroll
    for (int k = 0; k < F / 64; ++k) {
        const int idx = lane + k * 64;
        const float v = base[idx];
        // within-lane indices strictly increase, so '>' keeps first occurrence
        if (v > best) { best = v; bidx = idx; }
    }
    // 64-lane butterfly reduce; tie-break on smaller index (first occurrence)
#pragma unroll
    for (int off = 32; off >= 1; off >>= 1) {
        const float ov = __shfl_xor(best, off);
        const int   oi = __shfl_xor(bidx, off);
        if (ov > best || (ov == best && oi < bidx)) { best = ov; bidx = oi; }
    }
    if (lane == 0) {
        FP p;
        p.fidx = bidx;
        p.thr  = thr[row];
        packed[row] = p;
    }
}

// Kernel 2: one block per sample.
// Phase 1: stage x row (512 f32 = 2 KB) in LDS.
// Phase 2: thread t computes decision byte for tree t.
// Phase 3: threads re-layout as 16 tree-groups x 16 channels; coalesced 64 B
//          response gathers; two-level LDS reduction; write mean.
__global__ __launch_bounds__(256) void forest_kernel(
    const float* __restrict__ x,          // (B, F)
    const FP* __restrict__ packed,        // (T*D)
    const float* __restrict__ responses,  // (T, L, C)
    float* __restrict__ out)              // (B, C)
{
    __shared__ float xrow[F];
    __shared__ int   sdec[T];
    __shared__ float sacc[16][16];

    const int b   = blockIdx.x;
    const int tid = threadIdx.x;

    // Phase 1: cooperative coalesced load of the sample's feature row
    const float2 v2 = reinterpret_cast<const float2*>(x + (size_t)b * F)[tid];
    xrow[tid * 2]     = v2.x;
    xrow[tid * 2 + 1] = v2.y;
    __syncthreads();

    // Phase 2: decision for tree t = tid. 64 B contiguous node read/thread.
    const int2* p2 = reinterpret_cast<const int2*>(packed) + tid * D;
    int2 raw[D];
#pragma unroll
    for (int d = 0; d < D; ++d) raw[d] = p2[d];
    int dec = 0;
#pragma unroll
    for (int d = 0; d < D; ++d) {
        const float fv = xrow[raw[d].x];
        const float th = __int_as_float(raw[d].y);
        dec |= (fv > th) ? (128 >> d) : 0;   // powers = 2^(D-1-d)
    }
    sdec[tid] = dec;
    __syncthreads();

    // Phase 3: accumulate responses. group g handles trees [16g,16g+16),
    // channel c = tid&15 -> 16 consecutive lanes read one 64 B leaf row.
    const int g = tid >> 4;
    const int c = tid & 15;
    float acc = 0.0f;
#pragma unroll
    for (int k = 0; k < 16; ++k) {
        const int t  = g * 16 + k;
        const int dd = sdec[t];
        acc += responses[(size_t)((t << 8) | dd) * C + c];
    }
    sacc[g][c] = acc;
    __syncthreads();

    // Final reduce over the 16 groups; threads 0..15 (one per channel)
    if (tid < 16) {
        float s = 0.0f;
#pragma unroll
        for (int gg = 0; gg < 16; ++gg) s += sacc[gg][tid];
        out[(size_t)b * C + tid] = s * (1.0f / T);
    }
}

extern "C" void kernel_launch(void* const* d_in, const int* in_sizes, int n_in,
                              void* d_out, int out_size, void* d_ws, size_t ws_size,
                              hipStream_t stream) {
    const float* x         = (const float*)d_in[0];  // (B, F)
    const float* fw        = (const float*)d_in[1];  // (T, D, F)
    const float* thr       = (const float*)d_in[2];  // (T, D)
    const float* responses = (const float*)d_in[3];  // (T, L, C)
    float* out             = (float*)d_out;          // (B, C)

    FP* packed = (FP*)d_ws;                          // 16 KB scratch

    node_prep_kernel<<<(T * D) / 4, 256, 0, stream>>>(fw, thr, packed);
    forest_kernel<<<B, 256, 0, stream>>>(x, packed, responses, out);
}